// Round 19
// baseline (1000.330 us; speedup 1.0000x reference)
//
#include <hip/hip_runtime.h>
#include <hip/hip_bf16.h>

typedef __attribute__((ext_vector_type(4))) float f4;
typedef __attribute__((ext_vector_type(4))) short s4;
typedef __attribute__((ext_vector_type(8))) short s8;

#define SEQ 4096
#define DIM 1024
#define NB 8

__device__ inline short f2bf(float f) {
    return __builtin_bit_cast(short, __float2bfloat16(f));
}

__device__ inline float bf2f(short s) {
    return __builtin_bit_cast(float, (unsigned)((unsigned short)s) << 16);
}

__device__ inline void gload_lds16(const void* g, void* l) {
    __builtin_amdgcn_global_load_lds(
        (const __attribute__((address_space(1))) void*)g,
        (__attribute__((address_space(3))) void*)l, 16, 0, 0);
}

// ===========================================================================
// gemm256: C[M,N] = A[M,K] * B[N,K]^T. bf16 in, fp32 accum.
// 256x256 tile, BK=64, 8 waves (2Mx4N).
// NEW (r19): K-split half-unit pipeline = fine phases + COUNTED vmcnt —
// the one untested combination (r14 = counted w/o fine; r16 = fine w/o
// counted; m218/m196 say both are needed).
//   unit H = K-half (H&1) of tile (H>>1): A 256x32 + B 256x32 = 32 KB.
//   4-slot LDS ring (128 KB). Entering unit H: H landed, H+1/H+2 in flight.
//   Phases per H: ph0 {read B + A(m0-3) frags | stage A-part of H+3 |
//   barrier | lgkmcnt0 | 16 MFMA | barrier}; ph1 {read A(m4-7) | stage
//   B-part of H+3 | barrier | lgkmcnt0 | 16 MFMA}; end: vmcnt(8) + barrier
//   (H+1 landed, H+2/H+3 stay in flight — never drains in steady state).
// LDS slot layout (chunk-major, bank-conflict-free WITHOUT xor):
//   A: [j:rowhalf][chunk 0..3][row 0..127][16B] at j*8192+c*2048+r*16 bytes;
//   B: same at +16KB. Frag-read banks = (row*4)%32 -> 2-way (free, m136).
//   gload_lds dest stays linear (base + tid*16); the chunk permutation is
//   folded into the per-lane GLOBAL source address (rule #21).
// Accumulation order per acc[m][n]: kh0 then kh1 — identical to r17/r18 =>
// bit-identical output (absmax must remain exactly 1.953125e-3).
// Batched via blockIdx.y (ELEMENT strides). OUT: 0 = fp32 (+bias), 2 = bf16.
// ===========================================================================
template<int OUT>
__global__ __launch_bounds__(512, 2) void gemm256(
    const short* __restrict__ A, size_t lda, size_t bsA,
    const short* __restrict__ B, size_t ldb, size_t bsB,
    void* __restrict__ C, size_t ldc, size_t bsC,
    const float* __restrict__ bias, int nt, int gridN)
{
    __shared__ short lds[4 * 16384];   // 4 units x {A 8192, B 8192} shorts
    const int tid  = threadIdx.x;
    const int lane = tid & 63;
    const int wave = tid >> 6;

    A += (size_t)blockIdx.y * bsA;
    B += (size_t)blockIdx.y * bsB;
    float* Cf = (float*)C + (size_t)blockIdx.y * bsC;
    short* Cs = (short*)C + (size_t)blockIdx.y * bsC;

    const int nwg = gridDim.x;
    int wg = blockIdx.x;
    wg = (wg & 7) * (nwg >> 3) + (wg >> 3);   // bijective (nwg % 8 == 0)
    const size_t tm = (size_t)(wg / gridN) * 256;
    const size_t tn = (size_t)(wg % gridN) * 256;

    // Staging geometry: thread -> (row = tid&127, chunk = tid>>7).
    const int strow = tid & 127;
    const int schnk = tid >> 7;                // 0..3 (16B k-chunk)
    const short* pA = A + (tm + strow) * lda + schnk * 8;
    const short* pB = B + (tn + strow) * ldb + schnk * 8;
    const size_t a128 = (size_t)128 * lda;
    const size_t b128 = (size_t)128 * ldb;

    const int fr = lane & 15, kg = lane >> 4;  // frag row, 16B k-chunk
    const int wr = wave >> 2, wc = wave & 3;

    const int HMAX2 = 2 * nt;                  // number of half-units

    auto STAGE_A = [&](int h) {
        short* base = lds + (h & 3) * 16384;
        const size_t k0 = (size_t)(h >> 1) * 64 + (size_t)(h & 1) * 32;
        gload_lds16(pA + k0,        base + tid * 8);         // rows 0-127
        gload_lds16(pA + a128 + k0, base + 4096 + tid * 8);  // rows 128-255
    };
    auto STAGE_B = [&](int h) {
        short* base = lds + (h & 3) * 16384 + 8192;
        const size_t k0 = (size_t)(h >> 1) * 64 + (size_t)(h & 1) * 32;
        gload_lds16(pB + k0,        base + tid * 8);
        gload_lds16(pB + b128 + k0, base + 4096 + tid * 8);
    };

    f4 acc[8][4];
    #pragma unroll
    for (int m = 0; m < 8; ++m)
        #pragma unroll
        for (int n = 0; n < 4; ++n)
            acc[m][n] = (f4){0.f, 0.f, 0.f, 0.f};

    // Prologue: units 0,1,2 in flight (12 loads); wait unit 0 (oldest 4).
    STAGE_A(0); STAGE_B(0);
    STAGE_A(1); STAGE_B(1);
    STAGE_A(2); STAGE_B(2);
    asm volatile("s_waitcnt vmcnt(8)" ::: "memory");
    __builtin_amdgcn_s_barrier();
    __builtin_amdgcn_sched_barrier(0);

    for (int H = 0; H < HMAX2; ++H) {
        const short* sA = lds + (H & 3) * 16384 + wr * 4096 + kg * 1024;
        const short* sB = lds + (H & 3) * 16384 + 8192 + (wc >> 1) * 4096 + kg * 1024;
        const int brow0 = (wc & 1) * 64;

        // ---- phase 0: B frags + A frags m0-3; stage A-part of H+3
        s8 bf[4], af[4];
        #pragma unroll
        for (int n = 0; n < 4; ++n)
            bf[n] = *(const s8*)(sB + (brow0 + n * 16 + fr) * 8);
        #pragma unroll
        for (int m = 0; m < 4; ++m)
            af[m] = *(const s8*)(sA + (m * 16 + fr) * 8);
        if (H + 3 < HMAX2) STAGE_A(H + 3);

        __builtin_amdgcn_s_barrier();
        asm volatile("s_waitcnt lgkmcnt(0)" ::: "memory");
        __builtin_amdgcn_sched_barrier(0);
        __builtin_amdgcn_s_setprio(1);
        #pragma unroll
        for (int m = 0; m < 4; ++m)
            #pragma unroll
            for (int n = 0; n < 4; ++n)
                acc[m][n] = __builtin_amdgcn_mfma_f32_16x16x32_bf16(
                    af[m], bf[n], acc[m][n], 0, 0, 0);
        __builtin_amdgcn_s_setprio(0);
        __builtin_amdgcn_s_barrier();

        // ---- phase 1: A frags m4-7; stage B-part of H+3
        s8 ag[4];
        #pragma unroll
        for (int m = 0; m < 4; ++m)
            ag[m] = *(const s8*)(sA + ((m + 4) * 16 + fr) * 8);
        if (H + 3 < HMAX2) STAGE_B(H + 3);

        __builtin_amdgcn_s_barrier();
        asm volatile("s_waitcnt lgkmcnt(0)" ::: "memory");
        __builtin_amdgcn_sched_barrier(0);
        __builtin_amdgcn_s_setprio(1);
        #pragma unroll
        for (int m = 0; m < 4; ++m)
            #pragma unroll
            for (int n = 0; n < 4; ++n)
                acc[m + 4][n] = __builtin_amdgcn_mfma_f32_16x16x32_bf16(
                    ag[m], bf[n], acc[m + 4][n], 0, 0, 0);
        __builtin_amdgcn_s_setprio(0);

        // ---- end of unit H: counted wait (unit H+1 landed; rest in flight)
        if (H + 1 < HMAX2) {
            if (H + 3 < HMAX2) {
                asm volatile("s_waitcnt vmcnt(8)" ::: "memory");
            } else if (H + 2 < HMAX2) {
                asm volatile("s_waitcnt vmcnt(4)" ::: "memory");
            } else {
                asm volatile("s_waitcnt vmcnt(0)" ::: "memory");
            }
            __builtin_amdgcn_s_barrier();
            __builtin_amdgcn_sched_barrier(0);
        }
    }

    const int cg = lane >> 4, cl = lane & 15;
    #pragma unroll
    for (int m = 0; m < 8; ++m) {
        #pragma unroll
        for (int n = 0; n < 4; ++n) {
            const size_t grow = tm + wr * 128 + m * 16 + cg * 4;
            const size_t gcol = tn + wc * 64 + n * 16 + cl;
            float bv = 0.f;
            if constexpr (OUT == 0) { if (bias) bv = bias[gcol]; }
            #pragma unroll
            for (int i = 0; i < 4; ++i) {
                const float val = acc[m][n][i] + bv;
                if constexpr (OUT == 0)
                    Cf[(grow + i) * ldc + gcol] = val;
                else
                    Cs[(grow + i) * ldc + gcol] = f2bf(val);
            }
        }
    }
}

// fp32 -> bf16, 8 elements/thread (W only).
__global__ __launch_bounds__(256) void conv_bf16(const float* __restrict__ in,
                                                 short* __restrict__ out, int n8)
{
    const int i = blockIdx.x * 256 + threadIdx.x;
    if (i >= n8) return;
    f4 a = ((const f4*)in)[2 * i];
    f4 b = ((const f4*)in)[2 * i + 1];
    s8 w;
    w[0] = f2bf(a[0]); w[1] = f2bf(a[1]); w[2] = f2bf(a[2]); w[3] = f2bf(a[3]);
    w[4] = f2bf(b[0]); w[5] = f2bf(b[1]); w[6] = f2bf(b[2]); w[7] = f2bf(b[3]);
    ((s8*)out)[i] = w;
}

// ===========================================================================
// prep_batch4: one launch per GROUP of 4 batches (validated r18).
// ===========================================================================
__global__ __launch_bounds__(256) void prep_batch4(
    const float* __restrict__ Q4, const float* __restrict__ K4,
    const float* __restrict__ V4,
    short* __restrict__ Qb4, short* __restrict__ Kb4, short* __restrict__ VT4)
{
    const int tid = threadIdx.x;
    const int b4  = blockIdx.x >> 13;
    const int blk = blockIdx.x & 8191;
    const size_t io = (size_t)b4 * SEQ * DIM;

    if (blk < 4096) {
        const float* in = ((blk < 2048) ? Q4 : K4) + io;
        short* out      = ((blk < 2048) ? Qb4 : Kb4) + io;
        const int i = (blk & 2047) * 256 + tid;
        f4 a = ((const f4*)in)[2 * i];
        f4 b = ((const f4*)in)[2 * i + 1];
        s8 w;
        w[0] = f2bf(a[0]); w[1] = f2bf(a[1]); w[2] = f2bf(a[2]); w[3] = f2bf(a[3]);
        w[4] = f2bf(b[0]); w[5] = f2bf(b[1]); w[6] = f2bf(b[2]); w[7] = f2bf(b[3]);
        ((s8*)out)[i] = w;
    } else {
        __shared__ float t[32][33];
        const float* Vf = V4 + io;
        short* VT = VT4 + (size_t)b4 * DIM * SEQ;
        const int b2 = blk - 4096;
        const size_t k0 = (size_t)(b2 & 127) * 32;
        const size_t d0 = (size_t)(b2 >> 7) * 32;

        const int r = tid >> 3, c4 = (tid & 7) * 4;
        f4 x = *(const f4*)(Vf + (k0 + r) * DIM + d0 + c4);
        #pragma unroll
        for (int i = 0; i < 4; ++i) t[r][c4 + i] = x[i];
        __syncthreads();

        const int d = tid >> 3, kk = (tid & 7) * 4;
        s4 w;
        #pragma unroll
        for (int i = 0; i < 4; ++i) w[i] = f2bf(t[kk + i][d]);
        *(s4*)(VT + (d0 + d) * SEQ + k0 + kk) = w;
    }
}

// Single-batch prep (fallback path; validated r9-r17).
__global__ __launch_bounds__(256) void prep_batch(
    const float* __restrict__ Qf, const float* __restrict__ Kf,
    const float* __restrict__ Vf,
    short* __restrict__ Qb, short* __restrict__ Kb, short* __restrict__ VT)
{
    const int tid = threadIdx.x;
    const int blk = blockIdx.x;

    if (blk < 4096) {
        const float* in = (blk < 2048) ? Qf : Kf;
        short* out      = (blk < 2048) ? Qb : Kb;
        const int i = (blk & 2047) * 256 + tid;
        f4 a = ((const f4*)in)[2 * i];
        f4 b = ((const f4*)in)[2 * i + 1];
        s8 w;
        w[0] = f2bf(a[0]); w[1] = f2bf(a[1]); w[2] = f2bf(a[2]); w[3] = f2bf(a[3]);
        w[4] = f2bf(b[0]); w[5] = f2bf(b[1]); w[6] = f2bf(b[2]); w[7] = f2bf(b[3]);
        ((s8*)out)[i] = w;
    } else {
        __shared__ float t[32][33];
        const int b2 = blk - 4096;
        const size_t k0 = (size_t)(b2 & 127) * 32;
        const size_t d0 = (size_t)(b2 >> 7) * 32;

        const int r = tid >> 3, c4 = (tid & 7) * 4;
        f4 x = *(const f4*)(Vf + (k0 + r) * DIM + d0 + c4);
        #pragma unroll
        for (int i = 0; i < 4; ++i) t[r][c4 + i] = x[i];
        __syncthreads();

        const int d = tid >> 3, kk = (tid & 7) * 4;
        s4 w;
        #pragma unroll
        for (int i = 0; i < 4; ++i) w[i] = f2bf(t[kk + i][d]);
        *(s4*)(VT + (d0 + d) * SEQ + k0 + kk) = w;
    }
}

// Row softmax over 4096 bf16 scores (packed, ld 4096), y-batched over 4
// score slices of SEQ*SEQ. Validated structure (rounds 12/13/17).
__global__ __launch_bounds__(256) void softmax_rows_bf(short* __restrict__ scores)
{
    const int tid = threadIdx.x;
    short* srow = scores + (size_t)blockIdx.y * SEQ * SEQ + (size_t)blockIdx.x * SEQ;
    const float SCALE = 0.03125f;

    float v[16];
    float mx = -3.4e38f;
    #pragma unroll
    for (int j = 0; j < 4; ++j) {
        s4 h = *(const s4*)(srow + (size_t)(j * 256 + tid) * 4);
        #pragma unroll
        for (int i = 0; i < 4; ++i) {
            const float f = bf2f(h[i]) * SCALE;
            v[j * 4 + i] = f;
            mx = fmaxf(mx, f);
        }
    }
    #pragma unroll
    for (int o = 32; o > 0; o >>= 1) mx = fmaxf(mx, __shfl_xor(mx, o));
    __shared__ float red[4];
    if ((tid & 63) == 0) red[tid >> 6] = mx;
    __syncthreads();
    mx = fmaxf(fmaxf(red[0], red[1]), fmaxf(red[2], red[3]));

    float sum = 0.f;
    #pragma unroll
    for (int j = 0; j < 16; ++j) {
        const float e = __expf(v[j] - mx);
        v[j] = e;
        sum += e;
    }
    #pragma unroll
    for (int o = 32; o > 0; o >>= 1) sum += __shfl_xor(sum, o);
    __syncthreads();
    if ((tid & 63) == 0) red[tid >> 6] = sum;
    __syncthreads();
    const float inv = 1.f / (red[0] + red[1] + red[2] + red[3]);

    #pragma unroll
    for (int j = 0; j < 4; ++j) {
        s4 w;
        #pragma unroll
        for (int i = 0; i < 4; ++i) w[i] = f2bf(v[j * 4 + i] * inv);
        *(s4*)(srow + (size_t)(j * 256 + tid) * 4) = w;
    }
}

extern "C" void kernel_launch(void* const* d_in, const int* in_sizes, int n_in,
                              void* d_out, int out_size, void* d_ws, size_t ws_size,
                              hipStream_t stream) {
    const float* Q    = (const float*)d_in[0];
    const float* Km   = (const float*)d_in[1];
    const float* V    = (const float*)d_in[2];
    const float* W    = (const float*)d_in[3];
    const float* bias = (const float*)d_in[4];
    float* out = (float*)d_out;

    const dim3 blk256(256), blk512(512);
    // Big layout: ctx 64MB | VT4 32MB | Qb4 32MB | Kb4 32MB | Wb 2MB = 162 MB
    const size_t needBig =
        (size_t)NB * SEQ * DIM * 2 + (size_t)4 * DIM * SEQ * 2 +
        (size_t)4 * SEQ * DIM * 2 + (size_t)4 * SEQ * DIM * 2 +
        (size_t)DIM * DIM * 2;
    short* scoresB = (short*)d_out;   // 4 x 32 MB bf16 scores = 128 MiB

    if (ws_size >= needBig) {
        short* ctx = (short*)d_ws;
        short* VT4 = ctx + (size_t)NB * SEQ * DIM;
        short* Qb4 = VT4 + (size_t)4 * DIM * SEQ;
        short* Kb4 = Qb4 + (size_t)4 * SEQ * DIM;
        short* Wb  = Kb4 + (size_t)4 * SEQ * DIM;

        conv_bf16<<<DIM * DIM / 2048, blk256, 0, stream>>>(W, Wb, DIM * DIM / 8);

        for (int g = 0; g < 2; ++g) {
            const size_t go = (size_t)g * 4 * SEQ * DIM;
            prep_batch4<<<dim3(4 * 8192), blk256, 0, stream>>>(
                Q + go, Km + go, V + go, Qb4, Kb4, VT4);

            gemm256<2><<<dim3(256, 4), blk512, 0, stream>>>(
                Qb4, DIM, (size_t)SEQ * DIM,
                Kb4, DIM, (size_t)SEQ * DIM,
                scoresB, SEQ, (size_t)SEQ * SEQ,
                nullptr, DIM / 64, 16);

            softmax_rows_bf<<<dim3(SEQ, 4), blk256, 0, stream>>>(scoresB);

            gemm256<2><<<dim3(64, 4), blk512, 0, stream>>>(
                scoresB, SEQ, (size_t)SEQ * SEQ,
                VT4, SEQ, (size_t)DIM * SEQ,
                ctx + go, DIM, (size_t)SEQ * DIM,
                nullptr, SEQ / 64, 4);
        }
        gemm256<0><<<dim3(512, 1), blk512, 0, stream>>>(
            ctx, DIM, 0, Wb, DIM, 0, out, DIM, 0, bias, DIM / 64, 4);
    } else {
        // Fallback: round-17 flow (114 MB ws).
        short* ctx = (short*)d_ws;
        short* VT4 = ctx + (size_t)NB * SEQ * DIM;
        short* Qb  = VT4 + (size_t)4 * DIM * SEQ;
        short* Kb  = Qb + (size_t)SEQ * DIM;
        short* Wb  = Kb + (size_t)SEQ * DIM;

        conv_bf16<<<DIM * DIM / 2048, blk256, 0, stream>>>(W, Wb, DIM * DIM / 8);

        for (int g = 0; g < 2; ++g) {
            for (int b4 = 0; b4 < 4; ++b4) {
                const int b = g * 4 + b4;
                prep_batch<<<dim3(8192), blk256, 0, stream>>>(
                    Q + (size_t)b * SEQ * DIM, Km + (size_t)b * SEQ * DIM,
                    V + (size_t)b * SEQ * DIM,
                    Qb, Kb, VT4 + (size_t)b4 * DIM * SEQ);

                gemm256<2><<<dim3(256, 1), blk512, 0, stream>>>(
                    Qb, DIM, 0, Kb, DIM, 0,
                    scoresB + (size_t)b4 * SEQ * SEQ, SEQ, 0,
                    nullptr, DIM / 64, 16);
            }
            softmax_rows_bf<<<dim3(SEQ, 4), blk256, 0, stream>>>(scoresB);

            gemm256<2><<<dim3(64, 4), blk512, 0, stream>>>(
                scoresB, SEQ, (size_t)SEQ * SEQ,
                VT4, SEQ, (size_t)DIM * SEQ,
                ctx + (size_t)g * 4 * SEQ * DIM, DIM, (size_t)SEQ * DIM,
                nullptr, SEQ / 64, 4);
        }
        gemm256<0><<<dim3(512, 1), blk512, 0, stream>>>(
            ctx, DIM, 0, Wb, DIM, 0, out, DIM, 0, bias, DIM / 64, 4);
    }
}

// Round 20
// 771.848 us; speedup vs baseline: 1.2960x; 1.2960x over previous
//
#include <hip/hip_runtime.h>
#include <hip/hip_bf16.h>

typedef __attribute__((ext_vector_type(4))) float f4;
typedef __attribute__((ext_vector_type(4))) short s4;
typedef __attribute__((ext_vector_type(8))) short s8;

#define SEQ 4096
#define DIM 1024
#define NB 8

__device__ inline short f2bf(float f) {
    return __builtin_bit_cast(short, __float2bfloat16(f));
}

__device__ inline float bf2f(short s) {
    return __builtin_bit_cast(float, (unsigned)((unsigned short)s) << 16);
}

__device__ inline void gload_lds16(const void* g, void* l) {
    __builtin_amdgcn_global_load_lds(
        (const __attribute__((address_space(1))) void*)g,
        (__attribute__((address_space(3))) void*)l, 16, 0, 0);
}

// ===========================================================================
// gemm256: C[M,N] = A[M,K] * B[N,K]^T. bf16 in, fp32 accum.
// 256x256 tile, BK=64, 8 waves (2Mx4N), ring-2 LDS (128 KB), spill-proof
// drain schedule — the validated local optimum (r6/r11/r12/r13/r17/r18,
// best total 774 us). STAGE(t+1) before compute of tile t; ONE
// __syncthreads per K-step; compiler owns intra-iteration scheduling.
// Schedule-space probes all regressed: counted vmcnt (r14/r19), fine
// phases (r16/r19), 2 blocks/CU (r15) — do not re-attempt without the
// full co-designed m201 template.
// LDS row = 64 bf16 = 8 chunks of 16B; slot s at row r holds global chunk
// s ^ (r&7) (zero-conflict involution, measured r11-13).
// Batched via blockIdx.y: bsA/bsB/bsC are ELEMENT strides on typed pointers.
// OUT: 0 = fp32 (+bias if non-null), 2 = bf16.
// ===========================================================================
template<int OUT>
__global__ __launch_bounds__(512, 2) void gemm256(
    const short* __restrict__ A, size_t lda, size_t bsA,
    const short* __restrict__ B, size_t ldb, size_t bsB,
    void* __restrict__ C, size_t ldc, size_t bsC,
    const float* __restrict__ bias, int nt, int gridN)
{
    __shared__ short lds[2 * 32768];   // 2 bufs x {A 16384, B 16384} shorts
    const int tid  = threadIdx.x;
    const int lane = tid & 63;
    const int wave = tid >> 6;

    A += (size_t)blockIdx.y * bsA;
    B += (size_t)blockIdx.y * bsB;
    float* Cf = (float*)C + (size_t)blockIdx.y * bsC;
    short* Cs = (short*)C + (size_t)blockIdx.y * bsC;

    const int nwg = gridDim.x;
    int wg = blockIdx.x;
    wg = (wg & 7) * (nwg >> 3) + (wg >> 3);   // bijective (nwg % 8 == 0)
    const size_t tm = (size_t)(wg / gridN) * 256;
    const size_t tn = (size_t)(wg % gridN) * 256;

    const int srow = tid >> 3;                 // 0..63
    const int slot = tid & 7;
    const int sc   = slot ^ (srow & 7);
    const short* pA = A + (tm + srow) * lda + sc * 8;
    const short* pB = B + (tn + srow) * ldb + sc * 8;
    const int ldst = srow * 64 + slot * 8;

    const int fr = lane & 15, kg = lane >> 4;
    const int wr = wave >> 2, wc = wave & 3;

    auto STAGE = [&](int t) {
        short* bufA = lds + (t & 1) * 32768;
        short* bufB = bufA + 16384;
        const size_t k0 = (size_t)t * 64;
        #pragma unroll
        for (int j = 0; j < 4; ++j) {
            gload_lds16(pA + (size_t)(j * 64) * lda + k0, bufA + j * 4096 + ldst);
            gload_lds16(pB + (size_t)(j * 64) * ldb + k0, bufB + j * 4096 + ldst);
        }
    };

    f4 acc[8][4];
    #pragma unroll
    for (int m = 0; m < 8; ++m)
        #pragma unroll
        for (int n = 0; n < 4; ++n)
            acc[m][n] = (f4){0.f, 0.f, 0.f, 0.f};

    STAGE(0);
    __syncthreads();

    for (int t = 0; t < nt; ++t) {
        if (t + 1 < nt) STAGE(t + 1);

        const short* bufA = lds + (t & 1) * 32768;
        const short* bufB = bufA + 16384;
        s8 af[2][8], bf[2][4];
        #pragma unroll
        for (int kh = 0; kh < 2; ++kh) {
            #pragma unroll
            for (int m = 0; m < 8; ++m) {
                const int row = wr * 128 + m * 16 + fr;
                const int c   = kh * 4 + kg;
                af[kh][m] = *(const s8*)(bufA + row * 64 + (c ^ (row & 7)) * 8);
            }
            #pragma unroll
            for (int n = 0; n < 4; ++n) {
                const int row = wc * 64 + n * 16 + fr;
                const int c   = kh * 4 + kg;
                bf[kh][n] = *(const s8*)(bufB + row * 64 + (c ^ (row & 7)) * 8);
            }
        }
        __builtin_amdgcn_s_setprio(1);
        #pragma unroll
        for (int kh = 0; kh < 2; ++kh)
            #pragma unroll
            for (int m = 0; m < 8; ++m)
                #pragma unroll
                for (int n = 0; n < 4; ++n)
                    acc[m][n] = __builtin_amdgcn_mfma_f32_16x16x32_bf16(
                        af[kh][m], bf[kh][n], acc[m][n], 0, 0, 0);
        __builtin_amdgcn_s_setprio(0);

        __syncthreads();
    }

    const int cg = lane >> 4, cl = lane & 15;
    #pragma unroll
    for (int m = 0; m < 8; ++m) {
        #pragma unroll
        for (int n = 0; n < 4; ++n) {
            const size_t grow = tm + wr * 128 + m * 16 + cg * 4;
            const size_t gcol = tn + wc * 64 + n * 16 + cl;
            float bv = 0.f;
            if constexpr (OUT == 0) { if (bias) bv = bias[gcol]; }
            #pragma unroll
            for (int i = 0; i < 4; ++i) {
                const float val = acc[m][n][i] + bv;
                if constexpr (OUT == 0)
                    Cf[(grow + i) * ldc + gcol] = val;
                else
                    Cs[(grow + i) * ldc + gcol] = f2bf(val);
            }
        }
    }
}

// fp32 -> bf16, 8 elements/thread (W only).
__global__ __launch_bounds__(256) void conv_bf16(const float* __restrict__ in,
                                                 short* __restrict__ out, int n8)
{
    const int i = blockIdx.x * 256 + threadIdx.x;
    if (i >= n8) return;
    f4 a = ((const f4*)in)[2 * i];
    f4 b = ((const f4*)in)[2 * i + 1];
    s8 w;
    w[0] = f2bf(a[0]); w[1] = f2bf(a[1]); w[2] = f2bf(a[2]); w[3] = f2bf(a[3]);
    w[4] = f2bf(b[0]); w[5] = f2bf(b[1]); w[6] = f2bf(b[2]); w[7] = f2bf(b[3]);
    ((s8*)out)[i] = w;
}

// ===========================================================================
// prep_batch4: one launch per GROUP of 4 batches (Q-conv, K-conv, V-transpose
// for each). Grid 4 x 8192; blockIdx.x>>13 selects the batch slice.
// Bodies identical to the validated prep_batch.
// ===========================================================================
__global__ __launch_bounds__(256) void prep_batch4(
    const float* __restrict__ Q4, const float* __restrict__ K4,
    const float* __restrict__ V4,
    short* __restrict__ Qb4, short* __restrict__ Kb4, short* __restrict__ VT4)
{
    const int tid = threadIdx.x;
    const int b4  = blockIdx.x >> 13;
    const int blk = blockIdx.x & 8191;
    const size_t io = (size_t)b4 * SEQ * DIM;

    if (blk < 4096) {
        const float* in = ((blk < 2048) ? Q4 : K4) + io;
        short* out      = ((blk < 2048) ? Qb4 : Kb4) + io;
        const int i = (blk & 2047) * 256 + tid;
        f4 a = ((const f4*)in)[2 * i];
        f4 b = ((const f4*)in)[2 * i + 1];
        s8 w;
        w[0] = f2bf(a[0]); w[1] = f2bf(a[1]); w[2] = f2bf(a[2]); w[3] = f2bf(a[3]);
        w[4] = f2bf(b[0]); w[5] = f2bf(b[1]); w[6] = f2bf(b[2]); w[7] = f2bf(b[3]);
        ((s8*)out)[i] = w;
    } else {
        __shared__ float t[32][33];
        const float* Vf = V4 + io;
        short* VT = VT4 + (size_t)b4 * DIM * SEQ;
        const int b2 = blk - 4096;
        const size_t k0 = (size_t)(b2 & 127) * 32;
        const size_t d0 = (size_t)(b2 >> 7) * 32;

        const int r = tid >> 3, c4 = (tid & 7) * 4;
        f4 x = *(const f4*)(Vf + (k0 + r) * DIM + d0 + c4);
        #pragma unroll
        for (int i = 0; i < 4; ++i) t[r][c4 + i] = x[i];
        __syncthreads();

        const int d = tid >> 3, kk = (tid & 7) * 4;
        s4 w;
        #pragma unroll
        for (int i = 0; i < 4; ++i) w[i] = f2bf(t[kk + i][d]);
        *(s4*)(VT + (d0 + d) * SEQ + k0 + kk) = w;
    }
}

// Single-batch prep (fallback path; validated r9-r17).
__global__ __launch_bounds__(256) void prep_batch(
    const float* __restrict__ Qf, const float* __restrict__ Kf,
    const float* __restrict__ Vf,
    short* __restrict__ Qb, short* __restrict__ Kb, short* __restrict__ VT)
{
    const int tid = threadIdx.x;
    const int blk = blockIdx.x;

    if (blk < 4096) {
        const float* in = (blk < 2048) ? Qf : Kf;
        short* out      = (blk < 2048) ? Qb : Kb;
        const int i = (blk & 2047) * 256 + tid;
        f4 a = ((const f4*)in)[2 * i];
        f4 b = ((const f4*)in)[2 * i + 1];
        s8 w;
        w[0] = f2bf(a[0]); w[1] = f2bf(a[1]); w[2] = f2bf(a[2]); w[3] = f2bf(a[3]);
        w[4] = f2bf(b[0]); w[5] = f2bf(b[1]); w[6] = f2bf(b[2]); w[7] = f2bf(b[3]);
        ((s8*)out)[i] = w;
    } else {
        __shared__ float t[32][33];
        const int b2 = blk - 4096;
        const size_t k0 = (size_t)(b2 & 127) * 32;
        const size_t d0 = (size_t)(b2 >> 7) * 32;

        const int r = tid >> 3, c4 = (tid & 7) * 4;
        f4 x = *(const f4*)(Vf + (k0 + r) * DIM + d0 + c4);
        #pragma unroll
        for (int i = 0; i < 4; ++i) t[r][c4 + i] = x[i];
        __syncthreads();

        const int d = tid >> 3, kk = (tid & 7) * 4;
        s4 w;
        #pragma unroll
        for (int i = 0; i < 4; ++i) w[i] = f2bf(t[kk + i][d]);
        *(s4*)(VT + (d0 + d) * SEQ + k0 + kk) = w;
    }
}

// Row softmax over 4096 bf16 scores (packed, ld 4096), y-batched over 4
// score slices of SEQ*SEQ. Validated structure (rounds 12/13/17).
__global__ __launch_bounds__(256) void softmax_rows_bf(short* __restrict__ scores)
{
    const int tid = threadIdx.x;
    short* srow = scores + (size_t)blockIdx.y * SEQ * SEQ + (size_t)blockIdx.x * SEQ;
    const float SCALE = 0.03125f;

    float v[16];
    float mx = -3.4e38f;
    #pragma unroll
    for (int j = 0; j < 4; ++j) {
        s4 h = *(const s4*)(srow + (size_t)(j * 256 + tid) * 4);
        #pragma unroll
        for (int i = 0; i < 4; ++i) {
            const float f = bf2f(h[i]) * SCALE;
            v[j * 4 + i] = f;
            mx = fmaxf(mx, f);
        }
    }
    #pragma unroll
    for (int o = 32; o > 0; o >>= 1) mx = fmaxf(mx, __shfl_xor(mx, o));
    __shared__ float red[4];
    if ((tid & 63) == 0) red[tid >> 6] = mx;
    __syncthreads();
    mx = fmaxf(fmaxf(red[0], red[1]), fmaxf(red[2], red[3]));

    float sum = 0.f;
    #pragma unroll
    for (int j = 0; j < 16; ++j) {
        const float e = __expf(v[j] - mx);
        v[j] = e;
        sum += e;
    }
    #pragma unroll
    for (int o = 32; o > 0; o >>= 1) sum += __shfl_xor(sum, o);
    __syncthreads();
    if ((tid & 63) == 0) red[tid >> 6] = sum;
    __syncthreads();
    const float inv = 1.f / (red[0] + red[1] + red[2] + red[3]);

    #pragma unroll
    for (int j = 0; j < 4; ++j) {
        s4 w;
        #pragma unroll
        for (int i = 0; i < 4; ++i) w[i] = f2bf(v[j * 4 + i] * inv);
        *(s4*)(srow + (size_t)(j * 256 + tid) * 4) = w;
    }
}

extern "C" void kernel_launch(void* const* d_in, const int* in_sizes, int n_in,
                              void* d_out, int out_size, void* d_ws, size_t ws_size,
                              hipStream_t stream) {
    const float* Q    = (const float*)d_in[0];
    const float* Km   = (const float*)d_in[1];
    const float* V    = (const float*)d_in[2];
    const float* W    = (const float*)d_in[3];
    const float* bias = (const float*)d_in[4];
    float* out = (float*)d_out;

    const dim3 blk256(256), blk512(512);
    // Big layout: ctx 64MB | VT4 32MB | Qb4 32MB | Kb4 32MB | Wb 2MB = 162 MB
    const size_t needBig =
        (size_t)NB * SEQ * DIM * 2 + (size_t)4 * DIM * SEQ * 2 +
        (size_t)4 * SEQ * DIM * 2 + (size_t)4 * SEQ * DIM * 2 +
        (size_t)DIM * DIM * 2;
    // d_out holds bf16 scores for a group of 4 batches (4 x 32 MB = 128 MiB).
    short* scoresB = (short*)d_out;

    if (ws_size >= needBig) {
        short* ctx = (short*)d_ws;
        short* VT4 = ctx + (size_t)NB * SEQ * DIM;
        short* Qb4 = VT4 + (size_t)4 * DIM * SEQ;
        short* Kb4 = Qb4 + (size_t)4 * SEQ * DIM;
        short* Wb  = Kb4 + (size_t)4 * SEQ * DIM;

        conv_bf16<<<DIM * DIM / 2048, blk256, 0, stream>>>(W, Wb, DIM * DIM / 8);

        for (int g = 0; g < 2; ++g) {
            const size_t go = (size_t)g * 4 * SEQ * DIM;
            // prep all 4 batches of the group in one launch
            prep_batch4<<<dim3(4 * 8192), blk256, 0, stream>>>(
                Q + go, Km + go, V + go, Qb4, Kb4, VT4);

            // scores(bf16, raw) = Q*K^T, y-batched over 4 (grid 256x4 = 1024)
            gemm256<2><<<dim3(256, 4), blk512, 0, stream>>>(
                Qb4, DIM, (size_t)SEQ * DIM,
                Kb4, DIM, (size_t)SEQ * DIM,
                scoresB, SEQ, (size_t)SEQ * SEQ,
                nullptr, DIM / 64, 16);

            softmax_rows_bf<<<dim3(SEQ, 4), blk256, 0, stream>>>(scoresB);

            // ctx = P * VT^T, y-batched over 4 (grid 64x4 = 256 wgs)
            gemm256<2><<<dim3(64, 4), blk512, 0, stream>>>(
                scoresB, SEQ, (size_t)SEQ * SEQ,
                VT4, SEQ, (size_t)DIM * SEQ,
                ctx + go, DIM, (size_t)SEQ * DIM,
                nullptr, SEQ / 64, 4);
        }
        // proj: out = ctx * W^T + bias
        gemm256<0><<<dim3(512, 1), blk512, 0, stream>>>(
            ctx, DIM, 0, Wb, DIM, 0, out, DIM, 0, bias, DIM / 64, 4);
    } else {
        // Fallback: round-17 flow (114 MB ws).
        short* ctx = (short*)d_ws;
        short* VT4 = ctx + (size_t)NB * SEQ * DIM;
        short* Qb  = VT4 + (size_t)4 * DIM * SEQ;
        short* Kb  = Qb + (size_t)SEQ * DIM;
        short* Wb  = Kb + (size_t)SEQ * DIM;

        conv_bf16<<<DIM * DIM / 2048, blk256, 0, stream>>>(W, Wb, DIM * DIM / 8);

        for (int g = 0; g < 2; ++g) {
            for (int b4 = 0; b4 < 4; ++b4) {
                const int b = g * 4 + b4;
                prep_batch<<<dim3(8192), blk256, 0, stream>>>(
                    Q + (size_t)b * SEQ * DIM, Km + (size_t)b * SEQ * DIM,
                    V + (size_t)b * SEQ * DIM,
                    Qb, Kb, VT4 + (size_t)b4 * DIM * SEQ);

                gemm256<2><<<dim3(256, 1), blk512, 0, stream>>>(
                    Qb, DIM, 0, Kb, DIM, 0,
                    scoresB + (size_t)b4 * SEQ * SEQ, SEQ, 0,
                    nullptr, DIM / 64, 16);
            }
            softmax_rows_bf<<<dim3(SEQ, 4), blk256, 0, stream>>>(scoresB);

            gemm256<2><<<dim3(64, 4), blk512, 0, stream>>>(
                scoresB, SEQ, (size_t)SEQ * SEQ,
                VT4, SEQ, (size_t)DIM * SEQ,
                ctx + (size_t)g * 4 * SEQ * DIM, DIM, (size_t)SEQ * DIM,
                nullptr, SEQ / 64, 4);
        }
        gemm256<0><<<dim3(512, 1), blk512, 0, stream>>>(
            ctx, DIM, 0, Wb, DIM, 0, out, DIM, 0, bias, DIM / 64, 4);
    }
}